// Round 1
// baseline (409.370 us; speedup 1.0000x reference)
//
#include <hip/hip_runtime.h>
#include <hip/hip_bf16.h>
#include <math.h>

// Exact (erf-based) GELU, elementwise over 4*4096*4096 fp32.
// Memory-bound: 512 MiB total HBM traffic, floor ~85us at 6.3 TB/s.
// float4 vectorized loads/stores: 16 B/lane * 64 lanes = 1 KiB per wave access.

__global__ __launch_bounds__(256) void gelu_f32x4_kernel(
    const float4* __restrict__ x, float4* __restrict__ out, int n4) {
  int i = blockIdx.x * blockDim.x + threadIdx.x;
  if (i >= n4) return;
  float4 v = x[i];
  const float kInvSqrt2 = 0.70710678118654752440f;
  float4 r;
  r.x = 0.5f * v.x * (1.0f + erff(v.x * kInvSqrt2));
  r.y = 0.5f * v.y * (1.0f + erff(v.y * kInvSqrt2));
  r.z = 0.5f * v.z * (1.0f + erff(v.z * kInvSqrt2));
  r.w = 0.5f * v.w * (1.0f + erff(v.w * kInvSqrt2));
  out[i] = r;
}

// Tail (n not divisible by 4) — not hit for 4*4096*4096 but kept for safety.
__global__ void gelu_f32_tail_kernel(const float* __restrict__ x,
                                     float* __restrict__ out, int start, int n) {
  int i = start + blockIdx.x * blockDim.x + threadIdx.x;
  if (i >= n) return;
  float v = x[i];
  out[i] = 0.5f * v * (1.0f + erff(v * 0.70710678118654752440f));
}

extern "C" void kernel_launch(void* const* d_in, const int* in_sizes, int n_in,
                              void* d_out, int out_size, void* d_ws, size_t ws_size,
                              hipStream_t stream) {
  const float* x = (const float*)d_in[0];
  float* out = (float*)d_out;
  int n = in_sizes[0];
  int n4 = n / 4;

  if (n4 > 0) {
    int block = 256;
    int grid = (n4 + block - 1) / block;
    gelu_f32x4_kernel<<<grid, block, 0, stream>>>((const float4*)x, (float4*)out, n4);
  }
  int tail_start = n4 * 4;
  int tail = n - tail_start;
  if (tail > 0) {
    gelu_f32_tail_kernel<<<1, 64, 0, stream>>>(x, out, tail_start, n);
  }
}